// Round 7
// baseline (466.604 us; speedup 1.0000x reference)
//
#include <hip/hip_runtime.h>
#include <math.h>

#define L_DIM 8
#define T_DIM 128
#define S_DIM 128
#define SP1   129
#define NSTRIDE 132                    // staged row stride (bank-phase spread)
#define BIGF  1000000000.0f
#define EPSF  1e-5f
#define NTHREADS 1024
#define NWAVES 16

// ---- DPP cross-lane reductions on the VALU pipe ----
template<int CTRL>
__device__ __forceinline__ float dpp_add_part(float x) {
    int r = __builtin_amdgcn_update_dpp(0, __float_as_int(x), CTRL, 0xF, 0xF, false);
    return __int_as_float(r);
}
// Sum over each 16-lane row; total lands in lane (li==15) of each group.
__device__ __forceinline__ float dpp16Sum15(float x) {
    x += dpp_add_part<0x111>(x);  // row_shr:1
    x += dpp_add_part<0x112>(x);  // row_shr:2
    x += dpp_add_part<0x114>(x);  // row_shr:4
    x += dpp_add_part<0x118>(x);  // row_shr:8
    return x;
}
// Sum over 64 lanes; total lands in lane 63.
__device__ __forceinline__ float dppSum63(float x) {
    x += dpp_add_part<0x111>(x);
    x += dpp_add_part<0x112>(x);
    x += dpp_add_part<0x114>(x);
    x += dpp_add_part<0x118>(x);
    x += dpp_add_part<0x142>(x);  // row_bcast:15
    x += dpp_add_part<0x143>(x);  // row_bcast:31
    return x;
}
__device__ __forceinline__ float lane63(float x) {
    return __int_as_float(__builtin_amdgcn_readlane(__float_as_int(x), 63));
}

// ---- raw barriers ----
__device__ __forceinline__ void wg_bar() {
    asm volatile("s_waitcnt lgkmcnt(0)" ::: "memory");
    __builtin_amdgcn_s_barrier();
    asm volatile("" ::: "memory");
}

// async global->LDS, 4B per lane (global_load_lds_dword): dst+lane*4, src per-lane
__device__ __forceinline__ void gld_lds4(const float* g, float* l) {
    __builtin_amdgcn_global_load_lds(
        (const __attribute__((address_space(1))) void*)g,
        (__attribute__((address_space(3))) void*)l,
        4, 0, 0);
}

// t-qkv matvec rows straight from GLOBAL (L2-hot attn_t); 8 compute waves,
// group (wid,g) owns rows wid*16+g+4p, p=0..3. Row weights never persist.
__device__ __forceinline__ void mv_glb4(const float* __restrict__ mat,
                                        const float in[8], int li, int rb,
                                        float* __restrict__ dst) {
#pragma unroll
    for (int p = 0; p < 4; ++p) {
        int r = rb + 4 * p;
        const float* row = mat + (size_t)r * SP1;
        float acc = 0.0f;
#pragma unroll
        for (int e = 0; e < 8; ++e) acc = fmaf(row[li * 8 + e], in[e], acc);
        acc = dpp16Sum15(acc);
        if (li == 15) dst[r] = acc + row[128];
    }
}

// n-qkv matvec from staged LDS (rows stride NSTRIDE, bias in separate array)
__device__ __forceinline__ void mv_stage2(const float* __restrict__ mat,
                                          const float* __restrict__ biasArr,
                                          const float in[8], int li, int r_base,
                                          float* __restrict__ dst) {
#pragma unroll
    for (int p = 0; p < 2; ++p) {
        int r = r_base + p * 4;
        const float* row = mat + r * NSTRIDE;
        float acc = 0.0f;
#pragma unroll
        for (int e = 0; e < 8; ++e) acc = fmaf(row[li * 8 + e], in[e], acc);
        acc = dpp16Sum15(acc);
        if (li == 15) dst[r] = acc + biasArr[r];
    }
}

// n-qkv v-matvec from register-held rows
__device__ __forceinline__ void mv_regs(const float wv[2][8], const float wb[2],
                                        const float in[8], int li, int r_base,
                                        float* __restrict__ dst) {
#pragma unroll
    for (int p = 0; p < 2; ++p) {
        float acc = 0.0f;
#pragma unroll
        for (int e = 0; e < 8; ++e) acc = fmaf(wv[p][e], in[e], acc);
        acc = dpp16Sum15(acc);
        if (li == 15) dst[r_base + p * 4] = acc + wb[p];
    }
}

// t-softmax + @v + residual; 16 waves, rows r_base, r_base+4
__device__ __forceinline__ void attn_sm_t(int li, int r_base,
                                          const float* __restrict__ lds_q,
                                          const float* __restrict__ lds_k,
                                          const float* __restrict__ lds_v,
                                          const float* __restrict__ resid,
                                          float* __restrict__ lds_out)
{
    const float scale = 0.08838834764831845f; // rsqrt(128)
    float kx[8], vx[8];
#pragma unroll
    for (int e = 0; e < 8; ++e) { kx[e] = lds_k[li * 8 + e]; vx[e] = lds_v[li * 8 + e]; }
#pragma unroll
    for (int p = 0; p < 2; ++p) {
        int r = r_base + p * 4;
        float qs = lds_q[r] * scale;
        float den = 0.0f, num = 0.0f;
#pragma unroll
        for (int e = 0; e < 8; ++e) {
            float ee = __expf(qs * kx[e]);
            den += ee;
            num = fmaf(ee, vx[e], num);
        }
        den = dpp16Sum15(den);
        num = dpp16Sum15(num);
        if (li == 15) lds_out[r] = num / den + resid[r];
    }
}

__global__ __launch_bounds__(NTHREADS)
void net_kernel(const float* __restrict__ x,
                const float* __restrict__ W,
                const float* __restrict__ maskp,
                const float* __restrict__ attn_t,
                const float* __restrict__ attn_n,
                const float* __restrict__ norm_params,
                const float* __restrict__ ada,
                float* __restrict__ out,
                unsigned long long* __restrict__ mbox)
{
    const int t    = blockIdx.x;
    const int tid  = threadIdx.x;
    const int lane = tid & 63;
    const int wid  = tid >> 6;
    const int li   = lane & 15;
    const int g    = lane >> 4;
    const int r0   = wid * 8 + g;       // 16-wave row mapping (n-phase, t-softmax)
    const int r1   = r0 + 4;

    __shared__ float lds_nq[S_DIM * NSTRIDE];   // staged n-attn q rows (67.6 KB)
    __shared__ float lds_nk[S_DIM * NSTRIDE];   // staged n-attn k rows (67.6 KB)
    __shared__ float lds_nqb[S_DIM], lds_nkb[S_DIM];  // biases (gathered)
    __shared__ float lds_vals[S_DIM];
    __shared__ float lds_q[S_DIM], lds_k[S_DIM], lds_v[S_DIM];
    __shared__ float lds_tv[S_DIM];
    __shared__ float lds_aff[NWAVES];

    float nv[2][8];                             // n-attn v rows (0 if masked)
    float nvb0, nvb1;

    // ---- prologue: stagers (waves 8-15) stage FULL q,k of attn_n[0][t]
    //      (full => LDS never holds non-float garbage; later layers leave
    //      stale-but-finite floats in skipped rows). All waves prefetch v. ----
    {
        const float* srcn = attn_n + (size_t)t * 3 * S_DIM * SP1;
        if (wid >= 8) {
            if (wid == 8)  gld_lds4(srcn + (size_t)lane * SP1 + 128, lds_nqb);
            if (wid == 9)  gld_lds4(srcn + (size_t)(64 + lane) * SP1 + 128, lds_nqb + 64);
            if (wid == 10) gld_lds4(srcn + (size_t)(S_DIM + lane) * SP1 + 128, lds_nkb);
            if (wid == 11) gld_lds4(srcn + (size_t)(S_DIM + 64 + lane) * SP1 + 128, lds_nkb + 64);
            const float* kb_ = srcn + S_DIM * SP1;
#pragma unroll
            for (int k2 = 0; k2 < 16; ++k2) {
                int r = (wid - 8) + 8 * k2;     // wave-uniform row
                gld_lds4(srcn + (size_t)r * SP1 + lane,      lds_nq + r * NSTRIDE);
                gld_lds4(srcn + (size_t)r * SP1 + 64 + lane, lds_nq + r * NSTRIDE + 64);
                gld_lds4(kb_  + (size_t)r * SP1 + lane,      lds_nk + r * NSTRIDE);
                gld_lds4(kb_  + (size_t)r * SP1 + 64 + lane, lds_nk + r * NSTRIDE + 64);
            }
        }
        const float* vb_ = srcn + 2 * S_DIM * SP1;
#pragma unroll
        for (int e = 0; e < 8; ++e) {
            nv[0][e] = vb_[(size_t)r0 * SP1 + li * 8 + e];
            nv[1][e] = vb_[(size_t)r1 * SP1 + li * 8 + e];
        }
        nvb0 = vb_[(size_t)r0 * SP1 + 128];
        nvb1 = vb_[(size_t)r1 * SP1 + 128];
    }

    for (int b = 0; b < L_DIM; ++b) {
        // ---- 1+2: poll + gelu + LayerNorm — wave 0 only ----
        if (wid == 0) {
            float np00 = norm_params[(b * 2 + 0) * S_DIM + lane];
            float np10 = norm_params[(b * 2 + 0) * S_DIM + lane + 64];
            float np01 = norm_params[(b * 2 + 1) * S_DIM + lane];
            float np11 = norm_params[(b * 2 + 1) * S_DIM + lane + 64];
            float v0, v1;
            if (b == 0) {
                v0 = x[lane]; v1 = x[lane + 64];
            } else {
                float a00 = ada[((b - 1) * T_DIM + lane) * 2 + 0];
                float a01 = ada[((b - 1) * T_DIM + lane) * 2 + 1];
                float a10 = ada[((b - 1) * T_DIM + lane + 64) * 2 + 0];
                float a11 = ada[((b - 1) * T_DIM + lane + 64) * 2 + 1];
                const unsigned long long* mb_ = mbox + (size_t)(b - 1) * T_DIM;
                unsigned long long u0, u1;
                do {
                    u0 = __hip_atomic_load(&mb_[lane], __ATOMIC_RELAXED, __HIP_MEMORY_SCOPE_AGENT);
                    u1 = __hip_atomic_load(&mb_[lane + 64], __ATOMIC_RELAXED, __HIP_MEMORY_SCOPE_AGENT);
                } while ((unsigned int)(u0 >> 32) != (unsigned int)b ||
                         (unsigned int)(u1 >> 32) != (unsigned int)b);
                {
                    float z = __uint_as_float((unsigned int)u0) * a00;
                    float z3 = z * z * z;
                    v0 = 0.5f * z * (1.0f + tanhf(0.7978845608028654f * (z + 0.044715f * z3))) * a01;
                }
                {
                    float z = __uint_as_float((unsigned int)u1) * a10;
                    float z3 = z * z * z;
                    v1 = 0.5f * z * (1.0f + tanhf(0.7978845608028654f * (z + 0.044715f * z3))) * a11;
                }
            }
            float s  = dppSum63(v0 + v1);
            float mu = lane63(s) * (1.0f / 128.0f);
            float d0 = v0 - mu, d1 = v1 - mu;
            float s2 = dppSum63(fmaf(d0, d0, d1 * d1));
            float rstd = rsqrtf(lane63(s2) * (1.0f / 128.0f) + EPSF);
            lds_vals[lane]      = d0 * rstd * np00 + np01;
            lds_vals[lane + 64] = d1 * rstd * np10 + np11;
        }
        wg_bar(); // BAR_A: lds_vals ready

        // ---- 3: t-qkv — COMPUTE waves (0-7) only, 4 rows/group, from L2.
        //      Stager waves (8-15) issue/consume NO vmem between their stream
        //      issue and BAR_C, so in-order vmcnt never drains the stream. ----
        if (wid < 8) {
            float iv[8];
#pragma unroll
            for (int e = 0; e < 8; ++e) iv[e] = lds_vals[li * 8 + e];
            const float* bb = attn_t + (size_t)b * 3 * S_DIM * SP1;
            int rb = wid * 16 + g;
            mv_glb4(bb,                   iv, li, rb, lds_q);
            mv_glb4(bb + 1 * S_DIM * SP1, iv, li, rb, lds_k);
            mv_glb4(bb + 2 * S_DIM * SP1, iv, li, rb, lds_v);
        }
        wg_bar(); // BAR_B

        // ---- 4: t-softmax (all 16 waves; LDS-only) ----
        attn_sm_t(li, r0, lds_q, lds_k, lds_v, lds_vals, lds_tv);
        // BAR_C: only stagers drain vmcnt (their stream => staged q,k visible)
        if (wid >= 8) asm volatile("s_waitcnt vmcnt(0)" ::: "memory");
        wg_bar(); // BAR_C

        // ---- aux loads post-BAR_C (every wave vmcnt-clean here) ----
        const float* mrow = maskp + (size_t)(b * T_DIM + t) * S_DIM;
        const float* wrow = W + (size_t)(b * T_DIM + t) * SP1;
        float m1mj[8];
#pragma unroll
        for (int e = 0; e < 8; ++e) m1mj[e] = 1.0f - mrow[li * 8 + e];
        float mr0 = mrow[r0], mr1 = mrow[r1];
        float wr0 = wrow[r0], wr1 = wrow[r1];
        float wb  = (wid == 0) ? wrow[128] : 0.0f;

        // ---- 5: n-qkv: q,k from staged LDS, v from regs (all 16 waves) ----
        {
            float tvv[8];
#pragma unroll
            for (int e = 0; e < 8; ++e) tvv[e] = lds_tv[li * 8 + e];
            mv_stage2(lds_nq, lds_nqb, tvv, li, r0, lds_q);
            mv_stage2(lds_nk, lds_nkb, tvv, li, r0, lds_k);
            float bv[2] = { nvb0, nvb1 };
            mv_regs(nv, bv, tvv, li, r0, lds_v);
        }
        wg_bar(); // BAR_D: n-qkv done; lds_nq/nk free for restage

        // ---- restage b+1 with MASK-SKIP: masked rows of q,k are never loaded
        //      (stale finite floats remain; qs-select below neutralizes them);
        //      masked v rows become zeros. ~50% stream cut, bit-identical
        //      active-row math (masked terms are exact +0 in the same slots). ----
        if (b < L_DIM - 1) {
            const float* srcn = attn_n + (size_t)((b + 1) * T_DIM + t) * 3 * S_DIM * SP1;
            const float* mnx  = maskp + (size_t)((b + 1) * T_DIM + t) * S_DIM;
            // consume ALL next-mask values BEFORE issuing any prefetch/stream
            float mr0n = mnx[r0], mr1n = mnx[r1];
            float mml = (wid >= 8 && lane < 16) ? mnx[(wid - 8) + 8 * lane] : 0.0f;
            unsigned long long bal = __ballot(mml != 0.0f);
            bool a0 = (mr0n != 0.0f), a1 = (mr1n != 0.0f);
            // v prefetch (skip masked): issue now, consumed at n-qkv(b+1)
            const float* vb_ = srcn + 2 * S_DIM * SP1;
            if (a0) {
#pragma unroll
                for (int e = 0; e < 8; ++e) nv[0][e] = vb_[(size_t)r0 * SP1 + li * 8 + e];
                nvb0 = vb_[(size_t)r0 * SP1 + 128];
            } else {
#pragma unroll
                for (int e = 0; e < 8; ++e) nv[0][e] = 0.0f;
                nvb0 = 0.0f;
            }
            if (a1) {
#pragma unroll
                for (int e = 0; e < 8; ++e) nv[1][e] = vb_[(size_t)r1 * SP1 + li * 8 + e];
                nvb1 = vb_[(size_t)r1 * SP1 + 128];
            } else {
#pragma unroll
                for (int e = 0; e < 8; ++e) nv[1][e] = 0.0f;
                nvb1 = 0.0f;
            }
            // stager stream LAST (nothing consumes vmem after this until BAR_C)
            if (wid >= 8) {
                if (wid == 8)  gld_lds4(srcn + (size_t)lane * SP1 + 128, lds_nqb);
                if (wid == 9)  gld_lds4(srcn + (size_t)(64 + lane) * SP1 + 128, lds_nqb + 64);
                if (wid == 10) gld_lds4(srcn + (size_t)(S_DIM + lane) * SP1 + 128, lds_nkb);
                if (wid == 11) gld_lds4(srcn + (size_t)(S_DIM + 64 + lane) * SP1 + 128, lds_nkb + 64);
                const float* kb_ = srcn + S_DIM * SP1;
#pragma unroll
                for (int k2 = 0; k2 < 16; ++k2) {
                    if ((bal >> k2) & 1ull) {   // wave-uniform skip (SGPR ballot)
                        int r = (wid - 8) + 8 * k2;
                        gld_lds4(srcn + (size_t)r * SP1 + lane,      lds_nq + r * NSTRIDE);
                        gld_lds4(srcn + (size_t)r * SP1 + 64 + lane, lds_nq + r * NSTRIDE + 64);
                        gld_lds4(kb_  + (size_t)r * SP1 + lane,      lds_nk + r * NSTRIDE);
                        gld_lds4(kb_  + (size_t)r * SP1 + 64 + lane, lds_nk + r * NSTRIDE + 64);
                    }
                }
            }
        }

        // ---- 6: n-softmax (masked) + residual, fused aff partial ----
        {
            const float scale = 0.08838834764831845f;
            float kx[8], vx[8];
#pragma unroll
            for (int e = 0; e < 8; ++e) { kx[e] = lds_k[li * 8 + e]; vx[e] = lds_v[li * 8 + e]; }
            float o0 = 0.0f, o1 = 0.0f;
#pragma unroll
            for (int p = 0; p < 2; ++p) {
                int r = r0 + p * 4;
                float mrp = p ? mr1 : mr0;
                float qv = lds_q[r];
                // masked r: staged q-row may be stale garbage -> force qs=0
                // (den=128, num finite; result is *mr=0 anyway). Active r:
                // identical expression to previous rounds.
                float qs = (mrp == 0.0f) ? 0.0f : qv * scale;
                float bp = BIGF * mrp;
                float den = 0.0f, num = 0.0f;
#pragma unroll
                for (int e = 0; e < 8; ++e) {
                    float s_ = fmaf(-bp, m1mj[e], qs * kx[e]);
                    float ee = __expf(s_);
                    den += ee;
                    num = fmaf(ee, vx[e], num);
                }
                den = dpp16Sum15(den);
                num = dpp16Sum15(num);
                float o = num / den + lds_tv[r];  // valid in owner lane li==15
                if (p) o1 = o; else o0 = o;
            }
            float part = (li == 15) ? (wr0 * mr0 * o0 + wr1 * mr1 * o1) : 0.0f;
            part = dppSum63(part);
            if (lane == 63) lds_aff[wid] = part;
        }
        wg_bar(); // BAR_E

        // ---- 7: final aff reduce + publish (wave 0) ----
        if (wid == 0) {
            float pa = (lane < NWAVES) ? lds_aff[lane] : 0.0f;
            pa = dppSum63(pa);
            if (lane == 63) {
                float aff = pa + wb;
                if (b == L_DIM - 1) {
                    out[t] = aff;
                } else {
                    unsigned long long u =
                        ((unsigned long long)(unsigned int)(b + 1) << 32) |
                        (unsigned long long)__float_as_uint(aff);
                    __hip_atomic_store(&mbox[(size_t)b * T_DIM + t], u,
                                       __ATOMIC_RELAXED, __HIP_MEMORY_SCOPE_AGENT);
                }
            }
        }
        // WARs: lds_nq/nk rewritten only after BAR_D; lds_vals rewritten after
        // BAR_E (wave0, next layer top); lds_aff rewritten after BAR_D(b+1).
    }
}

extern "C" void kernel_launch(void* const* d_in, const int* in_sizes, int n_in,
                              void* d_out, int out_size, void* d_ws, size_t ws_size,
                              hipStream_t stream) {
    const float* x           = (const float*)d_in[0];
    const float* W           = (const float*)d_in[1];
    const float* maskp       = (const float*)d_in[2];
    const float* attn_t      = (const float*)d_in[3];
    const float* attn_n      = (const float*)d_in[4];
    // d_in[5] = attn_mask_n (67 MB) intentionally unused: recomputed from mask
    const float* norm_params = (const float*)d_in[6];
    const float* ada         = (const float*)d_in[7];
    float* out = (float*)d_out;

    unsigned long long* mbox = (unsigned long long*)d_ws; // 7 epochs x 128 slots x 8B

    hipMemsetAsync(d_ws, 0, (size_t)(L_DIM - 1) * T_DIM * sizeof(unsigned long long), stream);

    void* args[] = { (void*)&x, (void*)&W, (void*)&maskp, (void*)&attn_t, (void*)&attn_n,
                     (void*)&norm_params, (void*)&ada, (void*)&out, (void*)&mbox };
    hipLaunchCooperativeKernel((const void*)net_kernel, dim3(T_DIM), dim3(NTHREADS),
                               args, 0, stream);
}

// Round 8
// 422.532 us; speedup vs baseline: 1.1043x; 1.1043x over previous
//
#include <hip/hip_runtime.h>
#include <math.h>

#define L_DIM 8
#define T_DIM 128
#define S_DIM 128
#define SP1   129
#define BIGF  1000000000.0f
#define EPSF  1e-5f
#define NTHREADS 1024
#define NWAVES 16

// ---- DPP cross-lane reductions on the VALU pipe ----
template<int CTRL>
__device__ __forceinline__ float dpp_add_part(float x) {
    int r = __builtin_amdgcn_update_dpp(0, __float_as_int(x), CTRL, 0xF, 0xF, false);
    return __int_as_float(r);
}
// Sum over each 16-lane row; total lands in lane (li==15) of each group.
__device__ __forceinline__ float dpp16Sum15(float x) {
    x += dpp_add_part<0x111>(x);  // row_shr:1
    x += dpp_add_part<0x112>(x);  // row_shr:2
    x += dpp_add_part<0x114>(x);  // row_shr:4
    x += dpp_add_part<0x118>(x);  // row_shr:8
    return x;
}
// Sum over 64 lanes; total lands in lane 63.
__device__ __forceinline__ float dppSum63(float x) {
    x += dpp_add_part<0x111>(x);
    x += dpp_add_part<0x112>(x);
    x += dpp_add_part<0x114>(x);
    x += dpp_add_part<0x118>(x);
    x += dpp_add_part<0x142>(x);  // row_bcast:15
    x += dpp_add_part<0x143>(x);  // row_bcast:31
    return x;
}
__device__ __forceinline__ float lane63(float x) {
    return __int_as_float(__builtin_amdgcn_readlane(__float_as_int(x), 63));
}

// ---- raw barriers ----
__device__ __forceinline__ void wg_bar() {
    asm volatile("s_waitcnt lgkmcnt(0)" ::: "memory");
    __builtin_amdgcn_s_barrier();
    asm volatile("" ::: "memory");
}
__device__ __forceinline__ void wg_bar_vm() {
    asm volatile("s_waitcnt vmcnt(0) lgkmcnt(0)" ::: "memory");
    __builtin_amdgcn_s_barrier();
    asm volatile("" ::: "memory");
}

// async global->LDS (counts on vmcnt)
__device__ __forceinline__ void gld_lds16(const float* g, float* l) {
    __builtin_amdgcn_global_load_lds(
        (const __attribute__((address_space(1))) void*)g,
        (__attribute__((address_space(3))) void*)l,
        16, 0, 0);
}
__device__ __forceinline__ void gld_lds4(const float* g, float* l) {
    __builtin_amdgcn_global_load_lds(
        (const __attribute__((address_space(1))) void*)g,
        (__attribute__((address_space(3))) void*)l,
        4, 0, 0);
}

// Stage pair-chunk c (rows 2c, 2c+1 of a 128x129 matrix) into LDS chunk c
// (stride-128 rows). ONE gld_lds16 per chunk: lanes 0-31 carry row 2c, lanes
// 32-63 carry row 2c+1. Bank spread via 16B-block XOR swizzle by row, applied
// on the per-lane GLOBAL source (LDS dst stays linear: base + lane*16).
__device__ __forceinline__ void stage_pair(const float* __restrict__ src,
                                           float* __restrict__ lds, int c, int lane) {
    int r  = 2 * c + (lane >> 5);
    int lb = ((lane & 31) * 16) ^ ((r & 7) << 4);   // byte offset within row
    gld_lds16((const float*)((const char*)(src + (size_t)r * SP1) + lb),
              lds + c * 256);
}

// t-qkv matvec rows straight from GLOBAL (L2-hot attn_t); 16 waves, 2 rows/group.
__device__ __forceinline__ void mv_glb(const float* __restrict__ mat,
                                       const float in[8], int li, int r_base,
                                       float* __restrict__ dst) {
#pragma unroll
    for (int p = 0; p < 2; ++p) {
        int r = r_base + p * 4;
        const float* row = mat + (size_t)r * SP1;
        float acc = 0.0f;
#pragma unroll
        for (int e = 0; e < 8; ++e) acc = fmaf(row[li * 8 + e], in[e], acc);
        acc = dpp16Sum15(acc);
        if (li == 15) dst[r] = acc + row[128];
    }
}

// n-qkv matvec from the swizzled staged-LDS matrix (stride-128 rows, 16B-block
// XOR by row). Element order within 16B blocks is preserved -> fmaf sequence
// e=0..7 is bit-identical to the unswizzled version.
__device__ __forceinline__ void mv_stage_swz(const float* __restrict__ mat,
                                             const float* __restrict__ biasArr,
                                             const float in[8], int li, int r_base,
                                             float* __restrict__ dst) {
#pragma unroll
    for (int p = 0; p < 2; ++p) {
        int r = r_base + p * 4;
        const char* rowp = (const char*)(mat + (size_t)r * 128);
        int swz = (r & 7) << 4;
        const float4 a = *(const float4*)(rowp + (((li * 32)     ) ^ swz));
        const float4 b = *(const float4*)(rowp + (((li * 32) + 16) ^ swz));
        float acc = 0.0f;
        acc = fmaf(a.x, in[0], acc); acc = fmaf(a.y, in[1], acc);
        acc = fmaf(a.z, in[2], acc); acc = fmaf(a.w, in[3], acc);
        acc = fmaf(b.x, in[4], acc); acc = fmaf(b.y, in[5], acc);
        acc = fmaf(b.z, in[6], acc); acc = fmaf(b.w, in[7], acc);
        acc = dpp16Sum15(acc);
        if (li == 15) dst[r] = acc + biasArr[r];
    }
}

// n-qkv v-matvec from register-held rows
__device__ __forceinline__ void mv_regs(const float wv[2][8], const float wb[2],
                                        const float in[8], int li, int r_base,
                                        float* __restrict__ dst) {
#pragma unroll
    for (int p = 0; p < 2; ++p) {
        float acc = 0.0f;
#pragma unroll
        for (int e = 0; e < 8; ++e) acc = fmaf(wv[p][e], in[e], acc);
        acc = dpp16Sum15(acc);
        if (li == 15) dst[r_base + p * 4] = acc + wb[p];
    }
}

// t-softmax + @v + residual; 16 waves, rows r_base, r_base+4
__device__ __forceinline__ void attn_sm_t(int li, int r_base,
                                          const float* __restrict__ lds_q,
                                          const float* __restrict__ lds_k,
                                          const float* __restrict__ lds_v,
                                          const float* __restrict__ resid,
                                          float* __restrict__ lds_out)
{
    const float scale = 0.08838834764831845f; // rsqrt(128)
    float kx[8], vx[8];
#pragma unroll
    for (int e = 0; e < 8; ++e) { kx[e] = lds_k[li * 8 + e]; vx[e] = lds_v[li * 8 + e]; }
#pragma unroll
    for (int p = 0; p < 2; ++p) {
        int r = r_base + p * 4;
        float qs = lds_q[r] * scale;
        float den = 0.0f, num = 0.0f;
#pragma unroll
        for (int e = 0; e < 8; ++e) {
            float ee = __expf(qs * kx[e]);
            den += ee;
            num = fmaf(ee, vx[e], num);
        }
        den = dpp16Sum15(den);
        num = dpp16Sum15(num);
        if (li == 15) lds_out[r] = num / den + resid[r];
    }
}

__global__ __launch_bounds__(NTHREADS)
void net_kernel(const float* __restrict__ x,
                const float* __restrict__ W,
                const float* __restrict__ maskp,
                const float* __restrict__ attn_t,
                const float* __restrict__ attn_n,
                const float* __restrict__ norm_params,
                const float* __restrict__ ada,
                float* __restrict__ out,
                unsigned long long* __restrict__ mbox)
{
    const int t    = blockIdx.x;
    const int tid  = threadIdx.x;
    const int lane = tid & 63;
    const int wid  = tid >> 6;
    const int li   = lane & 15;
    const int g    = lane >> 4;
    const int r0   = wid * 8 + g;
    const int r1   = r0 + 4;

    __shared__ float lds_nq[S_DIM * 128];       // staged n-attn q (64 KB, swizzled)
    __shared__ float lds_nk[S_DIM * 128];       // staged n-attn k (64 KB, swizzled)
    __shared__ float lds_nqb[S_DIM], lds_nkb[S_DIM];  // biases
    __shared__ float lds_vals[S_DIM];
    __shared__ float lds_q[S_DIM], lds_k[S_DIM], lds_v[S_DIM];
    __shared__ float lds_tv[S_DIM];
    __shared__ float lds_aff[NWAVES];

    float nv[2][8];                             // n-attn v rows (0 if masked)
    float nvb0, nvb1;

    // ---- prologue: ALL waves stage FULL q,k of attn_n[0][t] (16B pair-chunks,
    //      8 chunks/wave) so LDS always holds finite floats; biases gathered by
    //      waves 12-15; all waves prefetch their v rows. ----
    {
        const float* srcn = attn_n + (size_t)t * 3 * S_DIM * SP1;
        const float* kb_  = srcn + S_DIM * SP1;
        if (wid == 12) gld_lds4(srcn + (size_t)lane * SP1 + 128, lds_nqb);
        if (wid == 13) gld_lds4(srcn + (size_t)(64 + lane) * SP1 + 128, lds_nqb + 64);
        if (wid == 14) gld_lds4(kb_  + (size_t)lane * SP1 + 128, lds_nkb);
        if (wid == 15) gld_lds4(kb_  + (size_t)(64 + lane) * SP1 + 128, lds_nkb + 64);
#pragma unroll
        for (int k2 = 0; k2 < 4; ++k2) {
            int c = wid + 16 * k2;
            stage_pair(srcn, lds_nq, c, lane);
            stage_pair(kb_,  lds_nk, c, lane);
        }
        const float* vb_ = srcn + 2 * S_DIM * SP1;
#pragma unroll
        for (int e = 0; e < 8; ++e) {
            nv[0][e] = vb_[(size_t)r0 * SP1 + li * 8 + e];
            nv[1][e] = vb_[(size_t)r1 * SP1 + li * 8 + e];
        }
        nvb0 = vb_[(size_t)r0 * SP1 + 128];
        nvb1 = vb_[(size_t)r1 * SP1 + 128];
    }

    for (int b = 0; b < L_DIM; ++b) {
        // ---- per-layer aux loads (L2/LLC; consume drains own stream remnant,
        //      absorbed by the poll window — round-6-verified placement) ----
        const float* mrow = maskp + (size_t)(b * T_DIM + t) * S_DIM;
        const float* wrow = W + (size_t)(b * T_DIM + t) * SP1;
        float m1mj[8];
#pragma unroll
        for (int e = 0; e < 8; ++e) m1mj[e] = 1.0f - mrow[li * 8 + e];
        float mr0 = mrow[r0], mr1 = mrow[r1];
        float wr0 = wrow[r0], wr1 = wrow[r1];
        float wb  = (wid == 0) ? wrow[128] : 0.0f;

        // ---- 1+2: poll + gelu + LayerNorm — wave 0 only ----
        if (wid == 0) {
            float np00 = norm_params[(b * 2 + 0) * S_DIM + lane];
            float np10 = norm_params[(b * 2 + 0) * S_DIM + lane + 64];
            float np01 = norm_params[(b * 2 + 1) * S_DIM + lane];
            float np11 = norm_params[(b * 2 + 1) * S_DIM + lane + 64];
            float v0, v1;
            if (b == 0) {
                v0 = x[lane]; v1 = x[lane + 64];
            } else {
                float a00 = ada[((b - 1) * T_DIM + lane) * 2 + 0];
                float a01 = ada[((b - 1) * T_DIM + lane) * 2 + 1];
                float a10 = ada[((b - 1) * T_DIM + lane + 64) * 2 + 0];
                float a11 = ada[((b - 1) * T_DIM + lane + 64) * 2 + 1];
                const unsigned long long* mb_ = mbox + (size_t)(b - 1) * T_DIM;
                unsigned long long u0, u1;
                do {
                    u0 = __hip_atomic_load(&mb_[lane], __ATOMIC_RELAXED, __HIP_MEMORY_SCOPE_AGENT);
                    u1 = __hip_atomic_load(&mb_[lane + 64], __ATOMIC_RELAXED, __HIP_MEMORY_SCOPE_AGENT);
                } while ((unsigned int)(u0 >> 32) != (unsigned int)b ||
                         (unsigned int)(u1 >> 32) != (unsigned int)b);
                {
                    float z = __uint_as_float((unsigned int)u0) * a00;
                    float z3 = z * z * z;
                    v0 = 0.5f * z * (1.0f + tanhf(0.7978845608028654f * (z + 0.044715f * z3))) * a01;
                }
                {
                    float z = __uint_as_float((unsigned int)u1) * a10;
                    float z3 = z * z * z;
                    v1 = 0.5f * z * (1.0f + tanhf(0.7978845608028654f * (z + 0.044715f * z3))) * a11;
                }
            }
            float s  = dppSum63(v0 + v1);
            float mu = lane63(s) * (1.0f / 128.0f);
            float d0 = v0 - mu, d1 = v1 - mu;
            float s2 = dppSum63(fmaf(d0, d0, d1 * d1));
            float rstd = rsqrtf(lane63(s2) * (1.0f / 128.0f) + EPSF);
            lds_vals[lane]      = d0 * rstd * np00 + np01;
            lds_vals[lane + 64] = d1 * rstd * np10 + np11;
        }
        wg_bar(); // BAR_A: lds_vals ready

        // ---- 3: t-qkv — all 16 waves, rows from L2 ----
        {
            float iv[8];
#pragma unroll
            for (int e = 0; e < 8; ++e) iv[e] = lds_vals[li * 8 + e];
            const float* bb = attn_t + (size_t)b * 3 * S_DIM * SP1;
            mv_glb(bb,                    iv, li, r0, lds_q);
            mv_glb(bb + 1 * S_DIM * SP1,  iv, li, r0, lds_k);
            mv_glb(bb + 2 * S_DIM * SP1,  iv, li, r0, lds_v);
        }
        wg_bar(); // BAR_B

        // ---- 4: t-softmax (unmasked) + residual ----
        attn_sm_t(li, r0, lds_q, lds_k, lds_v, lds_vals, lds_tv);
        wg_bar_vm(); // BAR_C: the one vmcnt drain — staged n q,k for b now visible

        // ---- 5: n-qkv: q,k from swizzled staged LDS, v from regs ----
        {
            float tvv[8];
#pragma unroll
            for (int e = 0; e < 8; ++e) tvv[e] = lds_tv[li * 8 + e];
            mv_stage_swz(lds_nq, lds_nqb, tvv, li, r0, lds_q);
            mv_stage_swz(lds_nk, lds_nkb, tvv, li, r0, lds_k);
            float bv[2] = { nvb0, nvb1 };
            mv_regs(nv, bv, tvv, li, r0, lds_v);
        }
        wg_bar(); // BAR_D: n-qkv done; lds_nq/nk free for restage

        // ---- restage b+1 with PAIR-SKIP (chunk skipped iff BOTH rows masked;
        //      25% of q,k chunks skip at p=0.5) + v-skip. All mask values are
        //      consumed BEFORE any stream vmem issues (in-order vmcnt). Stale
        //      skipped rows stay finite; qs-select + exact exp(-1e9)=+0 keep
        //      active-row math bit-identical. ----
        if (b < L_DIM - 1) {
            const float* srcn = attn_n + (size_t)((b + 1) * T_DIM + t) * 3 * S_DIM * SP1;
            const float* mnx  = maskp + (size_t)((b + 1) * T_DIM + t) * S_DIM;
            float mr0n = mnx[r0], mr1n = mnx[r1];
            bool pa = (mnx[2 * lane] != 0.0f) || (mnx[2 * lane + 1] != 0.0f);
            unsigned long long bal = __ballot(pa);
            bool a0 = (mr0n != 0.0f), a1 = (mr1n != 0.0f);
            // v prefetch with skip (consumed at n-qkv of b+1)
            const float* vb_ = srcn + 2 * S_DIM * SP1;
            if (a0) {
#pragma unroll
                for (int e = 0; e < 8; ++e) nv[0][e] = vb_[(size_t)r0 * SP1 + li * 8 + e];
                nvb0 = vb_[(size_t)r0 * SP1 + 128];
            } else {
#pragma unroll
                for (int e = 0; e < 8; ++e) nv[0][e] = 0.0f;
                nvb0 = 0.0f;
            }
            if (a1) {
#pragma unroll
                for (int e = 0; e < 8; ++e) nv[1][e] = vb_[(size_t)r1 * SP1 + li * 8 + e];
                nvb1 = vb_[(size_t)r1 * SP1 + 128];
            } else {
#pragma unroll
                for (int e = 0; e < 8; ++e) nv[1][e] = 0.0f;
                nvb1 = 0.0f;
            }
            // biases (one instr each, waves 12-15)
            const float* kb_ = srcn + S_DIM * SP1;
            if (wid == 12) gld_lds4(srcn + (size_t)lane * SP1 + 128, lds_nqb);
            if (wid == 13) gld_lds4(srcn + (size_t)(64 + lane) * SP1 + 128, lds_nqb + 64);
            if (wid == 14) gld_lds4(kb_  + (size_t)lane * SP1 + 128, lds_nkb);
            if (wid == 15) gld_lds4(kb_  + (size_t)(64 + lane) * SP1 + 128, lds_nkb + 64);
            // pair-chunk stream, ballot-skipped (wave-uniform branch)
#pragma unroll
            for (int k2 = 0; k2 < 4; ++k2) {
                int c = wid + 16 * k2;
                if ((bal >> c) & 1ull) {
                    stage_pair(srcn, lds_nq, c, lane);
                    stage_pair(kb_,  lds_nk, c, lane);
                }
            }
        }

        // ---- 6: n-softmax (masked) + residual, fused aff partial ----
        {
            const float scale = 0.08838834764831845f;
            float kx[8], vx[8];
#pragma unroll
            for (int e = 0; e < 8; ++e) { kx[e] = lds_k[li * 8 + e]; vx[e] = lds_v[li * 8 + e]; }
            float o0 = 0.0f, o1 = 0.0f;
#pragma unroll
            for (int p = 0; p < 2; ++p) {
                int r = r0 + p * 4;
                float mrp = p ? mr1 : mr0;
                float qv = lds_q[r];
                // masked r: staged q-row may be stale -> force qs=0 (result is
                // *mr=0 anyway). Active r: identical expression to round 6.
                float qs = (mrp == 0.0f) ? 0.0f : qv * scale;
                float bp = BIGF * mrp;
                float den = 0.0f, num = 0.0f;
#pragma unroll
                for (int e = 0; e < 8; ++e) {
                    float s_ = fmaf(-bp, m1mj[e], qs * kx[e]);
                    float ee = __expf(s_);
                    den += ee;
                    num = fmaf(ee, vx[e], num);
                }
                den = dpp16Sum15(den);
                num = dpp16Sum15(num);
                float o = num / den + lds_tv[r];  // valid in owner lane li==15
                if (p) o1 = o; else o0 = o;
            }
            float part = (li == 15) ? (wr0 * mr0 * o0 + wr1 * mr1 * o1) : 0.0f;
            part = dppSum63(part);
            if (lane == 63) lds_aff[wid] = part;
        }
        wg_bar(); // BAR_E

        // ---- 7: final aff reduce + publish (wave 0) ----
        if (wid == 0) {
            float pa2 = (lane < NWAVES) ? lds_aff[lane] : 0.0f;
            pa2 = dppSum63(pa2);
            if (lane == 63) {
                float aff = pa2 + wb;
                if (b == L_DIM - 1) {
                    out[t] = aff;
                } else {
                    unsigned long long u =
                        ((unsigned long long)(unsigned int)(b + 1) << 32) |
                        (unsigned long long)__float_as_uint(aff);
                    __hip_atomic_store(&mbox[(size_t)b * T_DIM + t], u,
                                       __ATOMIC_RELAXED, __HIP_MEMORY_SCOPE_AGENT);
                }
            }
        }
        // WARs: lds_nq/nk rewritten only after BAR_D; lds_vals rewritten by
        // wave0 after BAR_E (next layer top); lds_aff rewritten after BAR_D(b+1).
    }
}

extern "C" void kernel_launch(void* const* d_in, const int* in_sizes, int n_in,
                              void* d_out, int out_size, void* d_ws, size_t ws_size,
                              hipStream_t stream) {
    const float* x           = (const float*)d_in[0];
    const float* W           = (const float*)d_in[1];
    const float* maskp       = (const float*)d_in[2];
    const float* attn_t      = (const float*)d_in[3];
    const float* attn_n      = (const float*)d_in[4];
    // d_in[5] = attn_mask_n (67 MB) intentionally unused: recomputed from mask
    const float* norm_params = (const float*)d_in[6];
    const float* ada         = (const float*)d_in[7];
    float* out = (float*)d_out;

    unsigned long long* mbox = (unsigned long long*)d_ws; // 7 epochs x 128 slots x 8B

    hipMemsetAsync(d_ws, 0, (size_t)(L_DIM - 1) * T_DIM * sizeof(unsigned long long), stream);

    void* args[] = { (void*)&x, (void*)&W, (void*)&maskp, (void*)&attn_t, (void*)&attn_n,
                     (void*)&norm_params, (void*)&ada, (void*)&out, (void*)&mbox };
    hipLaunchCooperativeKernel((const void*)net_kernel, dim3(T_DIM), dim3(NTHREADS),
                               args, 0, stream);
}